// Round 6
// baseline (781.612 us; speedup 1.0000x reference)
//
#include <hip/hip_runtime.h>
#include <stdint.h>

// ===== LinearQ4_0: out[8192,11008] = x[8192,4096] * W^T, W q4_0 packed =====
#define IN_F   4096
#define OUT_F  11008
#define M_ROWS 8192
#define BM 256
#define BN 256
#define BK 64
#define NTILE_K (IN_F / BK)   // 64 K-tiles, 2 per iteration -> 32 iters

typedef __attribute__((ext_vector_type(4))) float  f32x4;
typedef __attribute__((ext_vector_type(4))) int    int4v;
typedef __attribute__((ext_vector_type(8))) unsigned short ushort8;
typedef __bf16 bf16x8 __attribute__((ext_vector_type(8)));

__device__ __forceinline__ unsigned short f2bf(float f) {
  unsigned int u = __builtin_bit_cast(unsigned int, f);
  u += 0x7fffu + ((u >> 16) & 1u);
  return (unsigned short)(u >> 16);
}

// ---- kernel 1: dequantize q4_0 -> bf16 W[OUT_F][IN_F] (nt loads: read-once) ----
__global__ __launch_bounds__(256) void dequant_q40(const int* __restrict__ w,
                                                   const float* __restrict__ sc,
                                                   unsigned short* __restrict__ wb) {
  const int total8 = (OUT_F * IN_F) / 8;
  for (int t = blockIdx.x * blockDim.x + threadIdx.x; t < total8;
       t += gridDim.x * blockDim.x) {
    const int f0  = t * 8;
    const int p   = f0 >> 7;
    const int nib = (f0 >> 6) & 1;
    const int j0  = f0 & 63;
    const float scale = sc[f0 >> 6];
    const int* src = w + p * 64 + j0;
    const int4v b0 = __builtin_nontemporal_load(reinterpret_cast<const int4v*>(src));
    const int4v b1 = __builtin_nontemporal_load(reinterpret_cast<const int4v*>(src + 4));
    ushort8 r;
#pragma unroll
    for (int e = 0; e < 4; ++e) {
      const int v0 = b0[e], v1 = b1[e];
      const int q0 = nib ? ((v0 << 28) >> 28) : (v0 >> 4);
      const int q1 = nib ? ((v1 << 28) >> 28) : (v1 >> 4);
      r[e]     = f2bf((float)q0 * scale);
      r[4 + e] = f2bf((float)q1 * scale);
    }
    *reinterpret_cast<ushort8*>(wb + f0) = r;
  }
}

// ---- kernel 2: x fp32 -> bf16 (nt loads: read-once) ----
__global__ __launch_bounds__(256) void cvt_x(const float* __restrict__ x,
                                             unsigned short* __restrict__ xb) {
  const int total8 = (M_ROWS * IN_F) / 8;
  for (int t = blockIdx.x * blockDim.x + threadIdx.x; t < total8;
       t += gridDim.x * blockDim.x) {
    const f32x4 a0 = __builtin_nontemporal_load(reinterpret_cast<const f32x4*>(x + t * 8));
    const f32x4 a1 = __builtin_nontemporal_load(reinterpret_cast<const f32x4*>(x + t * 8 + 4));
    ushort8 r;
#pragma unroll
    for (int e = 0; e < 4; ++e) {
      r[e]     = f2bf(a0[e]);
      r[4 + e] = f2bf(a1[e]);
    }
    *reinterpret_cast<ushort8*>(xb + t * 8) = r;
  }
}

// ---- async global -> LDS, 16 B per lane ----
__device__ __forceinline__ void gld16(const void* g, void* l) {
  __builtin_amdgcn_global_load_lds(
      (const __attribute__((address_space(1))) unsigned int*)(uintptr_t)g,
      (__attribute__((address_space(3))) unsigned int*)(unsigned int)(uintptr_t)l,
      16, 0, 0);
}

#define BAR() do { asm volatile("" ::: "memory"); __builtin_amdgcn_s_barrier(); \
                   asm volatile("" ::: "memory"); } while (0)

// ---- kernel 3: 8-phase schedule, stage-consolidated. 256x256, BK=64, 8 waves. ----
// Stages at P1{1A1,1B1}, P3{0A0',0B0'}, P5{0A1',0B1'}, P7{1A0',1B0'} (4 loads ea);
// waits vmcnt(4) at P4,P8 only. Steady-state guarantee ages (issue->drain):
//   P4-wait drains {P7'(age5), P1(age3)} -> 1A0,1B0 (used P5,P6), 1A1,1B1 (P7,P8);
//   P8-wait drains {P3(age5), P5(age3)} -> 0A0',0B0' (next P1,P2), 0A1',0B1' (next P3,P4).
// WAR (stage <- last reader, barrier between): P1<-P7/P8-top, P3<-P1/P2-top,
//   P5<-P3/P4-top, P7<-P5/P6-top. Tail iterations stage wrapped (unused) data, same WAR.
// LDS [buf][A|B][kh][256][32] 64B rows, swizzle chunk^=((row>>1)&3) (2 lanes/bank);
// linear gld dest + inverse-swizzled global source + same XOR on ds_read.
__global__ __launch_bounds__(512, 2) void gemm_bt(const unsigned short* __restrict__ A,
                                                  const unsigned short* __restrict__ B,
                                                  float* __restrict__ C) {
  __shared__ __align__(16) unsigned short lds[65536];  // 128 KB

  const int NT  = OUT_F / BN;              // 43
  const int nwg = (M_ROWS / BM) * NT;      // 1376, %8==0
  const int cpx = nwg >> 3;
  const int bid = blockIdx.x;
  const int swz = (bid & 7) * cpx + (bid >> 3);
  const int mt  = swz / NT;
  const int nt  = swz - mt * NT;

  const int tid  = threadIdx.x;
  const int lane = tid & 63;
  const int wid  = tid >> 6;      // 8 waves: 2 (M) x 4 (N)
  const int wr   = wid >> 2;      // 0..1 -> 128 rows
  const int wc   = wid & 3;       // 0..3 -> 64 cols

  // ---- staging: thread t -> row t>>2, phys chunk t&3; logical chunk = pc ^ ((row>>1)&3) ----
  const int r_st = tid >> 2;
  const int lc   = (tid & 3) ^ ((tid >> 3) & 3);
  const unsigned short* gA = A + (size_t)(mt * BM + r_st) * IN_F + lc * 8;
  const unsigned short* gB = B + (size_t)(nt * BM + r_st) * IN_F + lc * 8;
  unsigned short* ldsw = lds + tid * 8;   // linear dest within each 8KB sweep

  // region base (ushorts): buf*32768 + (B?16384:0) + kh*8192 ; sweep2 at +4096
#define STAGE_A(b, h, kk) do {                                              \
    unsigned short* d_ = ldsw + (b) * 32768 + (h) * 8192;                   \
    const unsigned short* s_ = gA + (kk) + (h) * 32;                        \
    gld16(s_, d_); gld16(s_ + (size_t)128 * IN_F, d_ + 4096);               \
  } while (0)
#define STAGE_B(b, h, kk) do {                                              \
    unsigned short* d_ = ldsw + (b) * 32768 + 16384 + (h) * 8192;           \
    const unsigned short* s_ = gB + (kk) + (h) * 32;                        \
    gld16(s_, d_); gld16(s_ + (size_t)128 * IN_F, d_ + 4096);               \
  } while (0)

  // ---- fragment reads: row (bits 0-3 = fr) -> chunk (kq ^ (fr>>1)&3) ----
  const int fr   = lane & 15;
  const int kq   = lane >> 4;
  const int coff = (kq ^ ((fr >> 1) & 3)) * 8;   // ushort offset within 32-col row

  bf16x8 afr[4], bfr[4];
#define RD_A(b, h, mq) do {                                                 \
    const unsigned short* p_ = lds + (b) * 32768 + (h) * 8192 + coff;       \
    _Pragma("unroll") for (int mm = 0; mm < 4; ++mm)                        \
      afr[mm] = *reinterpret_cast<const bf16x8*>(                           \
          p_ + (size_t)(wr * 128 + (mq) * 64 + mm * 16 + fr) * 32);         \
  } while (0)
#define RD_B(b, h) do {                                                     \
    const unsigned short* p_ = lds + (b) * 32768 + 16384 + (h) * 8192 + coff; \
    _Pragma("unroll") for (int nn = 0; nn < 4; ++nn)                        \
      bfr[nn] = *reinterpret_cast<const bf16x8*>(                           \
          p_ + (size_t)(wc * 64 + nn * 16 + fr) * 32);                      \
  } while (0)

  f32x4 acc[8][4] = {};
#define MFMA16(mq) do {                                                     \
    __builtin_amdgcn_s_setprio(1);                                          \
    _Pragma("unroll") for (int mm = 0; mm < 4; ++mm)                        \
      _Pragma("unroll") for (int nn = 0; nn < 4; ++nn)                      \
        acc[(mq)*4+mm][nn] = __builtin_amdgcn_mfma_f32_16x16x32_bf16(       \
            afr[mm], bfr[nn], acc[(mq)*4+mm][nn], 0, 0, 0);                 \
    __builtin_amdgcn_s_setprio(0);                                          \
  } while (0)

  // ---- prologue: T0 full + T1 kh0 (12 loads); vmcnt(4) -> T0 landed, T1kh0 in flight ----
  STAGE_A(0, 0, 0); STAGE_B(0, 0, 0); STAGE_A(0, 1, 0); STAGE_B(0, 1, 0);
  STAGE_A(1, 0, BK); STAGE_B(1, 0, BK);
  asm volatile("s_waitcnt vmcnt(4)" ::: "memory");
  BAR();

  for (int it = 0; it < NTILE_K / 2; ++it) {
    const int kt1 = ((2 * it + 1) & (NTILE_K - 1)) * BK;   // cur Tb
    const int kt2 = ((2 * it + 2) & (NTILE_K - 1)) * BK;   // next Ta
    const int kt3 = ((2 * it + 3) & (NTILE_K - 1)) * BK;   // next Tb

    // P1: Ta kh0 m0-3 ; stage Tb kh1 (A+B)
    RD_A(0, 0, 0); RD_B(0, 0);
    STAGE_A(1, 1, kt1); STAGE_B(1, 1, kt1);
    BAR(); MFMA16(0); BAR();
    // P2: Ta kh0 m4-7
    RD_A(0, 0, 1);
    BAR(); MFMA16(1); BAR();
    // P3: Ta kh1 m0-3 ; stage next-Ta kh0
    RD_A(0, 1, 0); RD_B(0, 1);
    STAGE_A(0, 0, kt2); STAGE_B(0, 0, kt2);
    BAR(); MFMA16(0); BAR();
    // P4: Ta kh1 m4-7 ; counted wait -> Tb fully resident for P5-P8
    RD_A(0, 1, 1);
    BAR(); MFMA16(1);
    asm volatile("s_waitcnt vmcnt(4)" ::: "memory");
    BAR();
    // P5: Tb kh0 m0-3 ; stage next-Ta kh1
    RD_A(1, 0, 0); RD_B(1, 0);
    STAGE_A(0, 1, kt2); STAGE_B(0, 1, kt2);
    BAR(); MFMA16(0); BAR();
    // P6: Tb kh0 m4-7
    RD_A(1, 0, 1);
    BAR(); MFMA16(1); BAR();
    // P7: Tb kh1 m0-3 ; stage next-Tb kh0
    RD_A(1, 1, 0); RD_B(1, 1);
    STAGE_A(1, 0, kt3); STAGE_B(1, 0, kt3);
    BAR(); MFMA16(0); BAR();
    // P8: Tb kh1 m4-7 ; counted wait -> next Ta fully resident
    RD_A(1, 1, 1);
    BAR(); MFMA16(1);
    asm volatile("s_waitcnt vmcnt(4)" ::: "memory");
    BAR();
  }

  // ---- epilogue: nt stores (don't thrash L3's A/B panels) ----
  const int col  = nt * BN + wc * 64 + fr;
  const int row0 = mt * BM + wr * 128 + (lane >> 4) * 4;
#pragma unroll
  for (int m = 0; m < 8; ++m) {
#pragma unroll
    for (int n = 0; n < 4; ++n) {
      float* cp = C + (size_t)(row0 + m * 16) * OUT_F + (col + n * 16);
#pragma unroll
      for (int r = 0; r < 4; ++r)
        __builtin_nontemporal_store(acc[m][n][r], cp + (size_t)r * OUT_F);
    }
  }
}

extern "C" void kernel_launch(void* const* d_in, const int* in_sizes, int n_in,
                              void* d_out, int out_size, void* d_ws, size_t ws_size,
                              hipStream_t stream) {
  const float* x = (const float*)d_in[0];
  const int*   w = (const int*)d_in[1];
  const float* s = (const float*)d_in[2];
  float*     out = (float*)d_out;

  unsigned short* wb = (unsigned short*)d_ws;             // bf16 W  [OUT_F][IN_F]
  unsigned short* xb = wb + (size_t)OUT_F * IN_F;         // bf16 x  [M_ROWS][IN_F]

  dequant_q40<<<dim3(2048), dim3(256), 0, stream>>>(w, s, wb);
  cvt_x<<<dim3(2048), dim3(256), 0, stream>>>(x, xb);
  gemm_bt<<<dim3((M_ROWS / BM) * (OUT_F / BN)), dim3(512), 0, stream>>>(xb, wb, out);
}

// Round 7
// 756.505 us; speedup vs baseline: 1.0332x; 1.0332x over previous
//
#include <hip/hip_runtime.h>
#include <stdint.h>

// ===== LinearQ4_0: out[8192,11008] = x[8192,4096] * W^T, W q4_0 packed =====
#define IN_F   4096
#define OUT_F  11008
#define M_ROWS 8192
#define BM 256
#define BN 256
#define BK 64
#define NTILE_K (IN_F / BK)   // 64 K-tiles, 2 per iteration -> 32 iters

typedef __attribute__((ext_vector_type(4))) float  f32x4;
typedef __attribute__((ext_vector_type(4))) int    int4v;
typedef __attribute__((ext_vector_type(8))) unsigned short ushort8;
typedef __bf16 bf16x8 __attribute__((ext_vector_type(8)));

__device__ __forceinline__ unsigned short f2bf(float f) {
  unsigned int u = __builtin_bit_cast(unsigned int, f);
  u += 0x7fffu + ((u >> 16) & 1u);
  return (unsigned short)(u >> 16);
}

// ---- kernel 1: dequantize q4_0 -> bf16 W[OUT_F][IN_F] (nt loads: read-once) ----
__global__ __launch_bounds__(256) void dequant_q40(const int* __restrict__ w,
                                                   const float* __restrict__ sc,
                                                   unsigned short* __restrict__ wb) {
  const int total8 = (OUT_F * IN_F) / 8;
  for (int t = blockIdx.x * blockDim.x + threadIdx.x; t < total8;
       t += gridDim.x * blockDim.x) {
    const int f0  = t * 8;
    const int p   = f0 >> 7;
    const int nib = (f0 >> 6) & 1;
    const int j0  = f0 & 63;
    const float scale = sc[f0 >> 6];
    const int* src = w + p * 64 + j0;
    const int4v b0 = __builtin_nontemporal_load(reinterpret_cast<const int4v*>(src));
    const int4v b1 = __builtin_nontemporal_load(reinterpret_cast<const int4v*>(src + 4));
    ushort8 r;
#pragma unroll
    for (int e = 0; e < 4; ++e) {
      const int v0 = b0[e], v1 = b1[e];
      const int q0 = nib ? ((v0 << 28) >> 28) : (v0 >> 4);
      const int q1 = nib ? ((v1 << 28) >> 28) : (v1 >> 4);
      r[e]     = f2bf((float)q0 * scale);
      r[4 + e] = f2bf((float)q1 * scale);
    }
    *reinterpret_cast<ushort8*>(wb + f0) = r;
  }
}

// ---- kernel 2: x fp32 -> bf16 (nt loads: read-once) ----
__global__ __launch_bounds__(256) void cvt_x(const float* __restrict__ x,
                                             unsigned short* __restrict__ xb) {
  const int total8 = (M_ROWS * IN_F) / 8;
  for (int t = blockIdx.x * blockDim.x + threadIdx.x; t < total8;
       t += gridDim.x * blockDim.x) {
    const f32x4 a0 = __builtin_nontemporal_load(reinterpret_cast<const f32x4*>(x + t * 8));
    const f32x4 a1 = __builtin_nontemporal_load(reinterpret_cast<const f32x4*>(x + t * 8 + 4));
    ushort8 r;
#pragma unroll
    for (int e = 0; e < 4; ++e) {
      r[e]     = f2bf(a0[e]);
      r[4 + e] = f2bf(a1[e]);
    }
    *reinterpret_cast<ushort8*>(xb + t * 8) = r;
  }
}

// ---- async global -> LDS, 16 B per lane ----
__device__ __forceinline__ void gld16(const void* g, void* l) {
  __builtin_amdgcn_global_load_lds(
      (const __attribute__((address_space(1))) unsigned int*)(uintptr_t)g,
      (__attribute__((address_space(3))) unsigned int*)(unsigned int)(uintptr_t)l,
      16, 0, 0);
}

#define BAR() do { asm volatile("" ::: "memory"); __builtin_amdgcn_s_barrier(); \
                   asm volatile("" ::: "memory"); } while (0)

// ---- kernel 3: 8-phase schedule, uniform deep counted waits. 256x256, BK=64. ----
// Stages (2 loads each): P1:1A1 P2:1B1 P3:0A0' P4:0B0' P5:0A1' P6:0B1' P7:1A0' P8:1B0'.
// Waits: vmcnt(8) at P2,P4,P6,P8. Steady state: 8-12 loads in flight; each wait
// drains exactly the 4 loads needed over the NEXT two phases, at age 4.5-5 phases:
//   P2 -> drains 0A1',0B1' (read P3,P4)   P4 -> drains 1A0',1B0' (read P5,P6)
//   P6 -> drains 1A1 ,1B1  (read P7,P8)   P8 -> drains 0A0',0B0' (read next P1,P2)
// WAR (stage <- last reader, >=1 barrier between): P1<-P8-top, P2<-P7-top, P3<-P2-top,
//   P4<-P1-top, P5<-P4-top, P6<-P3-top, P7<-P6-top, P8<-P5-top.  All hold.
// LDS [buf][A|B][kh][256][32] 64B rows, swizzle chunk^=((row>>1)&3) (2 lanes/bank);
// linear gld dest + inverse-swizzled global source + same XOR on ds_read.
__global__ __launch_bounds__(512, 2) void gemm_bt(const unsigned short* __restrict__ A,
                                                  const unsigned short* __restrict__ B,
                                                  float* __restrict__ C) {
  __shared__ __align__(16) unsigned short lds[65536];  // 128 KB

  const int NT  = OUT_F / BN;              // 43
  const int nwg = (M_ROWS / BM) * NT;      // 1376, %8==0
  const int cpx = nwg >> 3;
  const int bid = blockIdx.x;
  const int swz = (bid & 7) * cpx + (bid >> 3);
  const int mt  = swz / NT;
  const int nt  = swz - mt * NT;

  const int tid  = threadIdx.x;
  const int lane = tid & 63;
  const int wid  = tid >> 6;      // 8 waves: 2 (M) x 4 (N)
  const int wr   = wid >> 2;      // 0..1 -> 128 rows
  const int wc   = wid & 3;       // 0..3 -> 64 cols

  // ---- staging: thread t -> row t>>2, phys chunk t&3; logical chunk = pc ^ ((row>>1)&3) ----
  const int r_st = tid >> 2;
  const int lc   = (tid & 3) ^ ((tid >> 3) & 3);
  const unsigned short* gA = A + (size_t)(mt * BM + r_st) * IN_F + lc * 8;
  const unsigned short* gB = B + (size_t)(nt * BM + r_st) * IN_F + lc * 8;
  unsigned short* ldsw = lds + tid * 8;   // linear dest within each 8KB sweep

  // region base (ushorts): buf*32768 + (B?16384:0) + kh*8192 ; sweep2 at +4096
#define STAGE_A(b, h, kk) do {                                              \
    unsigned short* d_ = ldsw + (b) * 32768 + (h) * 8192;                   \
    const unsigned short* s_ = gA + (kk) + (h) * 32;                        \
    gld16(s_, d_); gld16(s_ + (size_t)128 * IN_F, d_ + 4096);               \
  } while (0)
#define STAGE_B(b, h, kk) do {                                              \
    unsigned short* d_ = ldsw + (b) * 32768 + 16384 + (h) * 8192;           \
    const unsigned short* s_ = gB + (kk) + (h) * 32;                        \
    gld16(s_, d_); gld16(s_ + (size_t)128 * IN_F, d_ + 4096);               \
  } while (0)

  // ---- fragment reads: row (bits 0-3 = fr) -> chunk (kq ^ (fr>>1)&3) ----
  const int fr   = lane & 15;
  const int kq   = lane >> 4;
  const int coff = (kq ^ ((fr >> 1) & 3)) * 8;   // ushort offset within 32-col row

  bf16x8 afr[4], bfr[4];
#define RD_A(b, h, mq) do {                                                 \
    const unsigned short* p_ = lds + (b) * 32768 + (h) * 8192 + coff;       \
    _Pragma("unroll") for (int mm = 0; mm < 4; ++mm)                        \
      afr[mm] = *reinterpret_cast<const bf16x8*>(                           \
          p_ + (size_t)(wr * 128 + (mq) * 64 + mm * 16 + fr) * 32);         \
  } while (0)
#define RD_B(b, h) do {                                                     \
    const unsigned short* p_ = lds + (b) * 32768 + 16384 + (h) * 8192 + coff; \
    _Pragma("unroll") for (int nn = 0; nn < 4; ++nn)                        \
      bfr[nn] = *reinterpret_cast<const bf16x8*>(                           \
          p_ + (size_t)(wc * 64 + nn * 16 + fr) * 32);                      \
  } while (0)

  f32x4 acc[8][4] = {};
#define MFMA16(mq) do {                                                     \
    __builtin_amdgcn_s_setprio(1);                                          \
    _Pragma("unroll") for (int mm = 0; mm < 4; ++mm)                        \
      _Pragma("unroll") for (int nn = 0; nn < 4; ++nn)                      \
        acc[(mq)*4+mm][nn] = __builtin_amdgcn_mfma_f32_16x16x32_bf16(       \
            afr[mm], bfr[nn], acc[(mq)*4+mm][nn], 0, 0, 0);                 \
    __builtin_amdgcn_s_setprio(0);                                          \
  } while (0)

#define VWAIT8() asm volatile("s_waitcnt vmcnt(8)" ::: "memory")

  // ---- prologue: T0 kh0 first, then T0 kh1 + T1 kh0; vmcnt(8) -> T0kh0 resident,
  //      in-flight = [0A1,0B1,1A0,1B0] = exactly the steady-state P8-exit condition ----
  STAGE_A(0, 0, 0); STAGE_B(0, 0, 0);
  STAGE_A(0, 1, 0); STAGE_B(0, 1, 0);
  STAGE_A(1, 0, BK); STAGE_B(1, 0, BK);
  VWAIT8();
  BAR();

  for (int it = 0; it < NTILE_K / 2; ++it) {
    const int kt1 = ((2 * it + 1) & (NTILE_K - 1)) * BK;   // cur Tb
    const int kt2 = ((2 * it + 2) & (NTILE_K - 1)) * BK;   // next Ta
    const int kt3 = ((2 * it + 3) & (NTILE_K - 1)) * BK;   // next Tb

    // P1: Ta kh0 m0-3 ; stage 1A1
    RD_A(0, 0, 0); RD_B(0, 0); STAGE_A(1, 1, kt1);
    BAR(); MFMA16(0); BAR();
    // P2: Ta kh0 m4-7 ; stage 1B1 ; wait -> 0A1',0B1' resident (oops: 0A1/0B1 cur)
    RD_A(0, 0, 1); STAGE_B(1, 1, kt1);
    BAR(); MFMA16(1); VWAIT8(); BAR();
    // P3: Ta kh1 m0-3 ; stage next 0A0
    RD_A(0, 1, 0); RD_B(0, 1); STAGE_A(0, 0, kt2);
    BAR(); MFMA16(0); BAR();
    // P4: Ta kh1 m4-7 ; stage next 0B0 ; wait -> 1A0,1B0 resident
    RD_A(0, 1, 1); STAGE_B(0, 0, kt2);
    BAR(); MFMA16(1); VWAIT8(); BAR();
    // P5: Tb kh0 m0-3 ; stage next 0A1
    RD_A(1, 0, 0); RD_B(1, 0); STAGE_A(0, 1, kt2);
    BAR(); MFMA16(0); BAR();
    // P6: Tb kh0 m4-7 ; stage next 0B1 ; wait -> 1A1,1B1 resident
    RD_A(1, 0, 1); STAGE_B(0, 1, kt2);
    BAR(); MFMA16(1); VWAIT8(); BAR();
    // P7: Tb kh1 m0-3 ; stage next 1A0
    RD_A(1, 1, 0); RD_B(1, 1); STAGE_A(1, 0, kt3);
    BAR(); MFMA16(0); BAR();
    // P8: Tb kh1 m4-7 ; stage next 1B0 ; wait -> next 0A0,0B0 resident
    RD_A(1, 1, 1); STAGE_B(1, 0, kt3);
    BAR(); MFMA16(1); VWAIT8(); BAR();
  }

  // ---- epilogue: plain stores (nt-store regressed WRITE_SIZE by 27% in R6) ----
  const int col  = nt * BN + wc * 64 + fr;
  const int row0 = mt * BM + wr * 128 + (lane >> 4) * 4;
#pragma unroll
  for (int m = 0; m < 8; ++m) {
#pragma unroll
    for (int n = 0; n < 4; ++n) {
      float* cp = C + (size_t)(row0 + m * 16) * OUT_F + (col + n * 16);
#pragma unroll
      for (int r = 0; r < 4; ++r) cp[(size_t)r * OUT_F] = acc[m][n][r];
    }
  }
}

extern "C" void kernel_launch(void* const* d_in, const int* in_sizes, int n_in,
                              void* d_out, int out_size, void* d_ws, size_t ws_size,
                              hipStream_t stream) {
  const float* x = (const float*)d_in[0];
  const int*   w = (const int*)d_in[1];
  const float* s = (const float*)d_in[2];
  float*     out = (float*)d_out;

  unsigned short* wb = (unsigned short*)d_ws;             // bf16 W  [OUT_F][IN_F]
  unsigned short* xb = wb + (size_t)OUT_F * IN_F;         // bf16 x  [M_ROWS][IN_F]

  dequant_q40<<<dim3(2048), dim3(256), 0, stream>>>(w, s, wb);
  cvt_x<<<dim3(2048), dim3(256), 0, stream>>>(x, xb);
  gemm_bt<<<dim3((M_ROWS / BM) * (OUT_F / BN)), dim3(512), 0, stream>>>(xb, wb, out);
}

// Round 8
// 743.782 us; speedup vs baseline: 1.0509x; 1.0171x over previous
//
#include <hip/hip_runtime.h>
#include <stdint.h>

// ===== LinearQ4_0: out[8192,11008] = x[8192,4096] * W^T, W q4_0 packed =====
#define IN_F   4096
#define OUT_F  11008
#define M_ROWS 8192
#define BM 256
#define BN 256
#define BK 64
#define NTILE_K (IN_F / BK)   // 64 K-tiles, 2 per iteration -> 32 iters

typedef __attribute__((ext_vector_type(4))) float  f32x4;
typedef __attribute__((ext_vector_type(4))) int    int4v;
typedef __attribute__((ext_vector_type(8))) unsigned short ushort8;
typedef __bf16 bf16x8 __attribute__((ext_vector_type(8)));

__device__ __forceinline__ unsigned short f2bf(float f) {
  unsigned int u = __builtin_bit_cast(unsigned int, f);
  u += 0x7fffu + ((u >> 16) & 1u);
  return (unsigned short)(u >> 16);
}

// ---- kernel 1: dequantize q4_0 -> bf16 W[OUT_F][IN_F] (nt loads: read-once) ----
__global__ __launch_bounds__(256) void dequant_q40(const int* __restrict__ w,
                                                   const float* __restrict__ sc,
                                                   unsigned short* __restrict__ wb) {
  const int total8 = (OUT_F * IN_F) / 8;
  for (int t = blockIdx.x * blockDim.x + threadIdx.x; t < total8;
       t += gridDim.x * blockDim.x) {
    const int f0  = t * 8;
    const int p   = f0 >> 7;
    const int nib = (f0 >> 6) & 1;
    const int j0  = f0 & 63;
    const float scale = sc[f0 >> 6];
    const int* src = w + p * 64 + j0;
    const int4v b0 = __builtin_nontemporal_load(reinterpret_cast<const int4v*>(src));
    const int4v b1 = __builtin_nontemporal_load(reinterpret_cast<const int4v*>(src + 4));
    ushort8 r;
#pragma unroll
    for (int e = 0; e < 4; ++e) {
      const int v0 = b0[e], v1 = b1[e];
      const int q0 = nib ? ((v0 << 28) >> 28) : (v0 >> 4);
      const int q1 = nib ? ((v1 << 28) >> 28) : (v1 >> 4);
      r[e]     = f2bf((float)q0 * scale);
      r[4 + e] = f2bf((float)q1 * scale);
    }
    *reinterpret_cast<ushort8*>(wb + f0) = r;
  }
}

// ---- kernel 2: x fp32 -> bf16 (nt loads: read-once) ----
__global__ __launch_bounds__(256) void cvt_x(const float* __restrict__ x,
                                             unsigned short* __restrict__ xb) {
  const int total8 = (M_ROWS * IN_F) / 8;
  for (int t = blockIdx.x * blockDim.x + threadIdx.x; t < total8;
       t += gridDim.x * blockDim.x) {
    const f32x4 a0 = __builtin_nontemporal_load(reinterpret_cast<const f32x4*>(x + t * 8));
    const f32x4 a1 = __builtin_nontemporal_load(reinterpret_cast<const f32x4*>(x + t * 8 + 4));
    ushort8 r;
#pragma unroll
    for (int e = 0; e < 4; ++e) {
      r[e]     = f2bf(a0[e]);
      r[4 + e] = f2bf(a1[e]);
    }
    *reinterpret_cast<ushort8*>(xb + t * 8) = r;
  }
}

// ---- async global -> LDS, 16 B per lane ----
__device__ __forceinline__ void gld16(const void* g, void* l) {
  __builtin_amdgcn_global_load_lds(
      (const __attribute__((address_space(1))) unsigned int*)(uintptr_t)g,
      (__attribute__((address_space(3))) unsigned int*)(unsigned int)(uintptr_t)l,
      16, 0, 0);
}

#define BAR() do { asm volatile("" ::: "memory"); __builtin_amdgcn_s_barrier(); \
                   asm volatile("" ::: "memory"); } while (0)

// ---- kernel 3: 8-phase, ONE barrier/phase. 256x256, BK=64, 8 waves. ----
// Phase = {RD frags ; STAGE (2 loads) ; [vmcnt(8) on even phases] ; BAR ; MFMA}.
// The wait sits BEFORE the barrier, so the barrier publishes residency to all
// waves; the post-MFMA barrier is gone -> a wave's RD/STAGE of phase P+1
// overlaps its SIMD-partner's MFMA of phase P. Barriers/iter: 16 -> 8.
// Residency ledger (12 outstanding at each wait; vmcnt(8) drains oldest 4):
//   P2: drains 0A1,0B1 (read P3,P4)   P4: drains 1A0,1B0 (read P5,P6)
//   P6: drains 1A1,1B1 (read P7,P8)   P8: drains 0A0',0B0' (read next P1,P2)
// Every read is >=1 barrier after its covering wait. WAR: every stage target's
// last reader is a phase-top read completed before a barrier the staging wave
// has crossed. Prologue (12 loads + vmcnt(8)) == steady-state P8-exit.
// LDS [buf][A|B][kh][256][32] 64B rows, swizzle chunk^=((row>>1)&3);
// linear gld dest + inverse-swizzled global source + same XOR on ds_read.
__global__ __launch_bounds__(512, 2) void gemm_bt(const unsigned short* __restrict__ A,
                                                  const unsigned short* __restrict__ B,
                                                  float* __restrict__ C) {
  __shared__ __align__(16) unsigned short lds[65536];  // 128 KB

  const int NT  = OUT_F / BN;              // 43
  const int nwg = (M_ROWS / BM) * NT;      // 1376, %8==0
  const int cpx = nwg >> 3;
  const int bid = blockIdx.x;
  const int swz = (bid & 7) * cpx + (bid >> 3);
  const int mt  = swz / NT;
  const int nt  = swz - mt * NT;

  const int tid  = threadIdx.x;
  const int lane = tid & 63;
  const int wid  = tid >> 6;      // 8 waves: 2 (M) x 4 (N)
  const int wr   = wid >> 2;      // 0..1 -> 128 rows
  const int wc   = wid & 3;       // 0..3 -> 64 cols

  // ---- staging: thread t -> row t>>2, phys chunk t&3; logical chunk = pc ^ ((row>>1)&3) ----
  const int r_st = tid >> 2;
  const int lc   = (tid & 3) ^ ((tid >> 3) & 3);
  const unsigned short* gA = A + (size_t)(mt * BM + r_st) * IN_F + lc * 8;
  const unsigned short* gB = B + (size_t)(nt * BM + r_st) * IN_F + lc * 8;
  unsigned short* ldsw = lds + tid * 8;   // linear dest within each 8KB sweep

  // region base (ushorts): buf*32768 + (B?16384:0) + kh*8192 ; sweep2 at +4096
#define STAGE_A(b, h, kk) do {                                              \
    unsigned short* d_ = ldsw + (b) * 32768 + (h) * 8192;                   \
    const unsigned short* s_ = gA + (kk) + (h) * 32;                        \
    gld16(s_, d_); gld16(s_ + (size_t)128 * IN_F, d_ + 4096);               \
  } while (0)
#define STAGE_B(b, h, kk) do {                                              \
    unsigned short* d_ = ldsw + (b) * 32768 + 16384 + (h) * 8192;           \
    const unsigned short* s_ = gB + (kk) + (h) * 32;                        \
    gld16(s_, d_); gld16(s_ + (size_t)128 * IN_F, d_ + 4096);               \
  } while (0)

  // ---- fragment reads: row (bits 0-3 = fr) -> chunk (kq ^ (fr>>1)&3) ----
  const int fr   = lane & 15;
  const int kq   = lane >> 4;
  const int coff = (kq ^ ((fr >> 1) & 3)) * 8;   // ushort offset within 32-col row

  bf16x8 afr[4], bfr[4];
#define RD_A(b, h, mq) do {                                                 \
    const unsigned short* p_ = lds + (b) * 32768 + (h) * 8192 + coff;       \
    _Pragma("unroll") for (int mm = 0; mm < 4; ++mm)                        \
      afr[mm] = *reinterpret_cast<const bf16x8*>(                           \
          p_ + (size_t)(wr * 128 + (mq) * 64 + mm * 16 + fr) * 32);         \
  } while (0)
#define RD_B(b, h) do {                                                     \
    const unsigned short* p_ = lds + (b) * 32768 + 16384 + (h) * 8192 + coff; \
    _Pragma("unroll") for (int nn = 0; nn < 4; ++nn)                        \
      bfr[nn] = *reinterpret_cast<const bf16x8*>(                           \
          p_ + (size_t)(wc * 64 + nn * 16 + fr) * 32);                      \
  } while (0)

  f32x4 acc[8][4] = {};
#define MFMA16(mq) do {                                                     \
    __builtin_amdgcn_s_setprio(1);                                          \
    _Pragma("unroll") for (int mm = 0; mm < 4; ++mm)                        \
      _Pragma("unroll") for (int nn = 0; nn < 4; ++nn)                      \
        acc[(mq)*4+mm][nn] = __builtin_amdgcn_mfma_f32_16x16x32_bf16(       \
            afr[mm], bfr[nn], acc[(mq)*4+mm][nn], 0, 0, 0);                 \
    __builtin_amdgcn_s_setprio(0);                                          \
  } while (0)

#define VWAIT8() asm volatile("s_waitcnt vmcnt(8)" ::: "memory")

  // ---- prologue: 12 loads; vmcnt(8) -> 0A0,0B0 resident; in-flight matches P8-exit ----
  STAGE_A(0, 0, 0); STAGE_B(0, 0, 0);
  STAGE_A(0, 1, 0); STAGE_B(0, 1, 0);
  STAGE_A(1, 0, BK); STAGE_B(1, 0, BK);
  VWAIT8();
  BAR();

  for (int it = 0; it < NTILE_K / 2; ++it) {
    const int kt1 = ((2 * it + 1) & (NTILE_K - 1)) * BK;   // cur Tb
    const int kt2 = ((2 * it + 2) & (NTILE_K - 1)) * BK;   // next Ta
    const int kt3 = ((2 * it + 3) & (NTILE_K - 1)) * BK;   // next Tb

    // P1: Ta kh0 m0-3 ; stage 1A1
    RD_A(0, 0, 0); RD_B(0, 0); STAGE_A(1, 1, kt1);
    BAR(); MFMA16(0);
    // P2: Ta kh0 m4-7 ; stage 1B1 ; wait publishes 0A1,0B1
    RD_A(0, 0, 1); STAGE_B(1, 1, kt1); VWAIT8();
    BAR(); MFMA16(1);
    // P3: Ta kh1 m0-3 ; stage next 0A0
    RD_A(0, 1, 0); RD_B(0, 1); STAGE_A(0, 0, kt2);
    BAR(); MFMA16(0);
    // P4: Ta kh1 m4-7 ; stage next 0B0 ; wait publishes 1A0,1B0
    RD_A(0, 1, 1); STAGE_B(0, 0, kt2); VWAIT8();
    BAR(); MFMA16(1);
    // P5: Tb kh0 m0-3 ; stage next 0A1
    RD_A(1, 0, 0); RD_B(1, 0); STAGE_A(0, 1, kt2);
    BAR(); MFMA16(0);
    // P6: Tb kh0 m4-7 ; stage next 0B1 ; wait publishes 1A1,1B1
    RD_A(1, 0, 1); STAGE_B(0, 1, kt2); VWAIT8();
    BAR(); MFMA16(1);
    // P7: Tb kh1 m0-3 ; stage next 1A0
    RD_A(1, 1, 0); RD_B(1, 1); STAGE_A(1, 0, kt3);
    BAR(); MFMA16(0);
    // P8: Tb kh1 m4-7 ; stage next 1B0 ; wait publishes next 0A0,0B0
    RD_A(1, 1, 1); STAGE_B(1, 0, kt3); VWAIT8();
    BAR(); MFMA16(1);
  }

  // ---- epilogue: plain stores (nt-store regressed WRITE_SIZE 27% in R6) ----
  const int col  = nt * BN + wc * 64 + fr;
  const int row0 = mt * BM + wr * 128 + (lane >> 4) * 4;
#pragma unroll
  for (int m = 0; m < 8; ++m) {
#pragma unroll
    for (int n = 0; n < 4; ++n) {
      float* cp = C + (size_t)(row0 + m * 16) * OUT_F + (col + n * 16);
#pragma unroll
      for (int r = 0; r < 4; ++r) cp[(size_t)r * OUT_F] = acc[m][n][r];
    }
  }
}

extern "C" void kernel_launch(void* const* d_in, const int* in_sizes, int n_in,
                              void* d_out, int out_size, void* d_ws, size_t ws_size,
                              hipStream_t stream) {
  const float* x = (const float*)d_in[0];
  const int*   w = (const int*)d_in[1];
  const float* s = (const float*)d_in[2];
  float*     out = (float*)d_out;

  unsigned short* wb = (unsigned short*)d_ws;             // bf16 W  [OUT_F][IN_F]
  unsigned short* xb = wb + (size_t)OUT_F * IN_F;         // bf16 x  [M_ROWS][IN_F]

  dequant_q40<<<dim3(2048), dim3(256), 0, stream>>>(w, s, wb);
  cvt_x<<<dim3(2048), dim3(256), 0, stream>>>(x, xb);
  gemm_bt<<<dim3((M_ROWS / BM) * (OUT_F / BN)), dim3(512), 0, stream>>>(xb, wb, out);
}